// Round 1
// baseline (283.224 us; speedup 1.0000x reference)
//
#include <hip/hip_runtime.h>
#include <hip/hip_bf16.h>
#include <stdint.h>

#define B_ 2
#define T_ 2048
#define C_ 1024
#define H_ 16
#define D_ 64
#define M_ (B_ * T_)  // 4096

typedef __bf16 bf16x8 __attribute__((ext_vector_type(8)));
typedef float f32x4 __attribute__((ext_vector_type(4)));

__device__ inline void gload_lds16(const void* g, void* l) {
  __builtin_amdgcn_global_load_lds(
      (const __attribute__((address_space(1))) void*)g,
      (__attribute__((address_space(3))) void*)l, 16, 0, 0);
}

// ---------------- fp32 -> bf16 convert ----------------
__global__ void cvt_f32_bf16(const float* __restrict__ in,
                             __hip_bfloat16* __restrict__ out, int n) {
  int i = (blockIdx.x * blockDim.x + threadIdx.x) * 4;
  int stride = gridDim.x * blockDim.x * 4;
  for (; i < n; i += stride) {
    float4 v = *(const float4*)(in + i);
    union { __hip_bfloat16 h[4]; ushort4 u; } cv;
    cv.h[0] = __float2bfloat16(v.x);
    cv.h[1] = __float2bfloat16(v.y);
    cv.h[2] = __float2bfloat16(v.z);
    cv.h[3] = __float2bfloat16(v.w);
    *(ushort4*)(out + i) = cv.u;
  }
}

// ---------------- QKV projection GEMM ----------------
// C[m,n] = sum_k X[m,k] * W[n,k]  (+bias[n]); scatter to [B,H,T,D] bf16.
__global__ __launch_bounds__(256) void gemm_qkv(
    const __hip_bfloat16* __restrict__ X,
    const __hip_bfloat16* __restrict__ Wq,
    const __hip_bfloat16* __restrict__ Wk,
    const __hip_bfloat16* __restrict__ Wv,
    const float* __restrict__ bq, const float* __restrict__ bv,
    __hip_bfloat16* __restrict__ Qo, __hip_bfloat16* __restrict__ Ko,
    __hip_bfloat16* __restrict__ Vo) {
  const int z = blockIdx.z;
  const __hip_bfloat16* W = (z == 0) ? Wq : (z == 1) ? Wk : Wv;
  const float* bias = (z == 0) ? bq : (z == 2) ? bv : nullptr;
  __hip_bfloat16* Out = (z == 0) ? Qo : (z == 1) ? Ko : Vo;

  const int bm = blockIdx.x, bn = blockIdx.y;
  const int tid = threadIdx.x;
  const int w = tid >> 6, lane = tid & 63;
  const int wr = w >> 1, wc = w & 1;
  const int lrow = lane & 15, lk = (lane >> 4) * 8;

  __shared__ __hip_bfloat16 As[128 * 32];
  __shared__ __hip_bfloat16 Bs[128 * 32];

  f32x4 acc[4][4];
#pragma unroll
  for (int m = 0; m < 4; ++m)
#pragma unroll
    for (int n = 0; n < 4; ++n) acc[m][n] = (f32x4){0.f, 0.f, 0.f, 0.f};

  for (int k0 = 0; k0 < C_; k0 += 32) {
#pragma unroll
    for (int it = 0; it < 2; ++it) {
      int e = it * 2048 + w * 512 + lane * 8;
      int row = e >> 5, col = e & 31;
      gload_lds16(X + (size_t)(bm * 128 + row) * C_ + k0 + col, &As[e]);
      gload_lds16(W + (size_t)(bn * 128 + row) * C_ + k0 + col, &Bs[e]);
    }
    asm volatile("s_waitcnt vmcnt(0)" ::: "memory");
    __syncthreads();

    bf16x8 af[4], bfr[4];
#pragma unroll
    for (int m = 0; m < 4; ++m)
      af[m] = *(const bf16x8*)&As[(wr * 64 + m * 16 + lrow) * 32 + lk];
#pragma unroll
    for (int n = 0; n < 4; ++n)
      bfr[n] = *(const bf16x8*)&Bs[(wc * 64 + n * 16 + lrow) * 32 + lk];
#pragma unroll
    for (int m = 0; m < 4; ++m)
#pragma unroll
      for (int n = 0; n < 4; ++n)
        acc[m][n] = __builtin_amdgcn_mfma_f32_16x16x32_bf16(af[m], bfr[n],
                                                            acc[m][n], 0, 0, 0);
    __syncthreads();
  }

#pragma unroll
  for (int m = 0; m < 4; ++m) {
#pragma unroll
    for (int n = 0; n < 4; ++n) {
      f32x4 v = acc[m][n];
      int coln = bn * 128 + wc * 64 + n * 16 + (lane & 15);
      float bb = bias ? bias[coln] : 0.f;
      int h = coln >> 6, d = coln & 63;
#pragma unroll
      for (int r = 0; r < 4; ++r) {
        int row = bm * 128 + wr * 64 + m * 16 + (lane >> 4) * 4 + r;
        int b = row >> 11, t = row & 2047;
        Out[(((size_t)(b * H_ + h)) * T_ + t) * D_ + d] =
            __float2bfloat16(v[r] + bb);
      }
    }
  }
}

// ---------------- output projection GEMM (fp32 out) ----------------
__global__ __launch_bounds__(256) void gemm_out(
    const __hip_bfloat16* __restrict__ X,  // Y [4096,1024] bf16
    const __hip_bfloat16* __restrict__ W,  // Wo bf16 [1024,1024]
    const float* __restrict__ bias, float* __restrict__ Out) {
  const int bm = blockIdx.x, bn = blockIdx.y;
  const int tid = threadIdx.x;
  const int w = tid >> 6, lane = tid & 63;
  const int wr = w >> 1, wc = w & 1;
  const int lrow = lane & 15, lk = (lane >> 4) * 8;

  __shared__ __hip_bfloat16 As[128 * 32];
  __shared__ __hip_bfloat16 Bs[128 * 32];

  f32x4 acc[4][4];
#pragma unroll
  for (int m = 0; m < 4; ++m)
#pragma unroll
    for (int n = 0; n < 4; ++n) acc[m][n] = (f32x4){0.f, 0.f, 0.f, 0.f};

  for (int k0 = 0; k0 < C_; k0 += 32) {
#pragma unroll
    for (int it = 0; it < 2; ++it) {
      int e = it * 2048 + w * 512 + lane * 8;
      int row = e >> 5, col = e & 31;
      gload_lds16(X + (size_t)(bm * 128 + row) * C_ + k0 + col, &As[e]);
      gload_lds16(W + (size_t)(bn * 128 + row) * C_ + k0 + col, &Bs[e]);
    }
    asm volatile("s_waitcnt vmcnt(0)" ::: "memory");
    __syncthreads();

    bf16x8 af[4], bfr[4];
#pragma unroll
    for (int m = 0; m < 4; ++m)
      af[m] = *(const bf16x8*)&As[(wr * 64 + m * 16 + lrow) * 32 + lk];
#pragma unroll
    for (int n = 0; n < 4; ++n)
      bfr[n] = *(const bf16x8*)&Bs[(wc * 64 + n * 16 + lrow) * 32 + lk];
#pragma unroll
    for (int m = 0; m < 4; ++m)
#pragma unroll
      for (int n = 0; n < 4; ++n)
        acc[m][n] = __builtin_amdgcn_mfma_f32_16x16x32_bf16(af[m], bfr[n],
                                                            acc[m][n], 0, 0, 0);
    __syncthreads();
  }

#pragma unroll
  for (int m = 0; m < 4; ++m) {
#pragma unroll
    for (int n = 0; n < 4; ++n) {
      f32x4 v = acc[m][n];
      int coln = bn * 128 + wc * 64 + n * 16 + (lane & 15);
      float bb = bias[coln];
#pragma unroll
      for (int r = 0; r < 4; ++r) {
        int row = bm * 128 + wr * 64 + m * 16 + (lane >> 4) * 4 + r;
        Out[(size_t)row * C_ + coln] = v[r] + bb;
      }
    }
  }
}

// ---------------- flash attention (causal) ----------------
// grid (T/64, B*H); 4 waves, each owns 16 q-rows. KBLK=64.
__global__ __launch_bounds__(256) void attn_fwd(
    const __hip_bfloat16* __restrict__ Q, const __hip_bfloat16* __restrict__ K,
    const __hip_bfloat16* __restrict__ V, __hip_bfloat16* __restrict__ Y) {
  const int qt = blockIdx.x;
  const int bh = blockIdx.y;
  const int tid = threadIdx.x;
  const int w = tid >> 6, lane = tid & 63;
  const int lrow = lane & 15, lk = (lane >> 4) * 8;
  const int qbase = qt * 64;
  const size_t base = (size_t)bh * T_ * D_;

  __shared__ __hip_bfloat16 Qs[64][72];
  __shared__ __hip_bfloat16 Ks[64][72];
  __shared__ __hip_bfloat16 Vts[64][72];
  __shared__ __hip_bfloat16 Ps[4][16][72];

#pragma unroll
  for (int it = 0; it < 2; ++it) {
    int e = it * 2048 + tid * 8;
    int r = e >> 6, d = e & 63;
    *(uint4*)&Qs[r][d] = *(const uint4*)&Q[base + (size_t)(qbase + r) * D_ + d];
  }
  __syncthreads();

  bf16x8 qf0 = *(const bf16x8*)&Qs[w * 16 + lrow][lk];
  bf16x8 qf1 = *(const bf16x8*)&Qs[w * 16 + lrow][lk + 32];

  f32x4 o[4];
#pragma unroll
  for (int jd = 0; jd < 4; ++jd) o[jd] = (f32x4){0.f, 0.f, 0.f, 0.f};
  float m_run[4], l_run[4];
#pragma unroll
  for (int r = 0; r < 4; ++r) {
    m_run[r] = -__builtin_inff();
    l_run[r] = 0.f;
  }

  for (int kt = 0; kt <= qt; ++kt) {
#pragma unroll
    for (int it = 0; it < 2; ++it) {
      int e = it * 2048 + tid * 8;
      int r = e >> 6, d = e & 63;
      *(uint4*)&Ks[r][d] =
          *(const uint4*)&K[base + (size_t)(kt * 64 + r) * D_ + d];
    }
    for (int idx = tid; idx < 4096; idx += 256) {
      int kv = idx >> 6, d = idx & 63;
      Vts[d][kv] = V[base + (size_t)(kt * 64 + kv) * D_ + d];
    }
    __syncthreads();

    f32x4 s[4];
#pragma unroll
    for (int j = 0; j < 4; ++j) {
      bf16x8 b0 = *(const bf16x8*)&Ks[j * 16 + lrow][lk];
      bf16x8 b1 = *(const bf16x8*)&Ks[j * 16 + lrow][lk + 32];
      f32x4 a = (f32x4){0.f, 0.f, 0.f, 0.f};
      a = __builtin_amdgcn_mfma_f32_16x16x32_bf16(qf0, b0, a, 0, 0, 0);
      a = __builtin_amdgcn_mfma_f32_16x16x32_bf16(qf1, b1, a, 0, 0, 0);
      s[j] = a;
    }

    const bool diag = (kt == qt);
    float pmax[4] = {-__builtin_inff(), -__builtin_inff(), -__builtin_inff(),
                     -__builtin_inff()};
#pragma unroll
    for (int j = 0; j < 4; ++j)
#pragma unroll
      for (int r = 0; r < 4; ++r) {
        float sv = s[j][r] * 0.125f;
        if (diag) {
          int kvl = j * 16 + (lane & 15);
          int ql = w * 16 + (lane >> 4) * 4 + r;
          if (kvl > ql) sv = -__builtin_inff();
        }
        s[j][r] = sv;
        pmax[r] = fmaxf(pmax[r], sv);
      }
#pragma unroll
    for (int off = 1; off < 16; off <<= 1)
#pragma unroll
      for (int r = 0; r < 4; ++r)
        pmax[r] = fmaxf(pmax[r], __shfl_xor(pmax[r], off, 64));

    float alpha[4];
#pragma unroll
    for (int r = 0; r < 4; ++r) {
      float mn = fmaxf(m_run[r], pmax[r]);
      alpha[r] = __expf(m_run[r] - mn);
      m_run[r] = mn;
    }

    float lsum[4] = {0.f, 0.f, 0.f, 0.f};
#pragma unroll
    for (int j = 0; j < 4; ++j)
#pragma unroll
      for (int r = 0; r < 4; ++r) {
        float p = __expf(s[j][r] - m_run[r]);
        s[j][r] = p;
        lsum[r] += p;
      }
#pragma unroll
    for (int off = 1; off < 16; off <<= 1)
#pragma unroll
      for (int r = 0; r < 4; ++r) lsum[r] += __shfl_xor(lsum[r], off, 64);
#pragma unroll
    for (int r = 0; r < 4; ++r) l_run[r] = l_run[r] * alpha[r] + lsum[r];

#pragma unroll
    for (int jd = 0; jd < 4; ++jd)
#pragma unroll
      for (int r = 0; r < 4; ++r) o[jd][r] *= alpha[r];

#pragma unroll
    for (int j = 0; j < 4; ++j)
#pragma unroll
      for (int r = 0; r < 4; ++r)
        Ps[w][(lane >> 4) * 4 + r][j * 16 + (lane & 15)] =
            __float2bfloat16(s[j][r]);
    asm volatile("s_waitcnt lgkmcnt(0)" ::: "memory");
    __builtin_amdgcn_sched_barrier(0);

    bf16x8 pa0 = *(const bf16x8*)&Ps[w][lrow][lk];
    bf16x8 pa1 = *(const bf16x8*)&Ps[w][lrow][lk + 32];
#pragma unroll
    for (int jd = 0; jd < 4; ++jd) {
      bf16x8 v0 = *(const bf16x8*)&Vts[jd * 16 + lrow][lk];
      bf16x8 v1 = *(const bf16x8*)&Vts[jd * 16 + lrow][lk + 32];
      o[jd] = __builtin_amdgcn_mfma_f32_16x16x32_bf16(pa0, v0, o[jd], 0, 0, 0);
      o[jd] = __builtin_amdgcn_mfma_f32_16x16x32_bf16(pa1, v1, o[jd], 0, 0, 0);
    }
    __syncthreads();
  }

  const int b = bh >> 4, h = bh & 15;
#pragma unroll
  for (int r = 0; r < 4; ++r) {
    float inv = 1.0f / l_run[r];
    int qrow = qbase + w * 16 + (lane >> 4) * 4 + r;
#pragma unroll
    for (int jd = 0; jd < 4; ++jd) {
      int d = jd * 16 + (lane & 15);
      Y[((size_t)b * T_ + qrow) * C_ + h * D_ + d] =
          __float2bfloat16(o[jd][r] * inv);
    }
  }
}

extern "C" void kernel_launch(void* const* d_in, const int* in_sizes, int n_in,
                              void* d_out, int out_size, void* d_ws,
                              size_t ws_size, hipStream_t stream) {
  const float* x = (const float*)d_in[0];
  const float* Wk = (const float*)d_in[1];
  const float* Wq = (const float*)d_in[2];
  const float* bq = (const float*)d_in[3];
  const float* Wv = (const float*)d_in[4];
  const float* bv = (const float*)d_in[5];
  const float* Wo = (const float*)d_in[6];
  const float* bo = (const float*)d_in[7];
  float* out = (float*)d_out;

  char* ws = (char*)d_ws;
  __hip_bfloat16* xb = (__hip_bfloat16*)(ws);
  __hip_bfloat16* wqb = (__hip_bfloat16*)(ws + (8ull << 20));
  __hip_bfloat16* wkb = (__hip_bfloat16*)(ws + (10ull << 20));
  __hip_bfloat16* wvb = (__hip_bfloat16*)(ws + (12ull << 20));
  __hip_bfloat16* wob = (__hip_bfloat16*)(ws + (14ull << 20));
  __hip_bfloat16* Qb = (__hip_bfloat16*)(ws + (16ull << 20));
  __hip_bfloat16* Kb = (__hip_bfloat16*)(ws + (24ull << 20));
  __hip_bfloat16* Vb = (__hip_bfloat16*)(ws + (32ull << 20));
  __hip_bfloat16* Yb = (__hip_bfloat16*)(ws + (40ull << 20));

  cvt_f32_bf16<<<1024, 256, 0, stream>>>(x, xb, M_ * C_);
  cvt_f32_bf16<<<512, 256, 0, stream>>>(Wq, wqb, C_ * C_);
  cvt_f32_bf16<<<512, 256, 0, stream>>>(Wk, wkb, C_ * C_);
  cvt_f32_bf16<<<512, 256, 0, stream>>>(Wv, wvb, C_ * C_);
  cvt_f32_bf16<<<512, 256, 0, stream>>>(Wo, wob, C_ * C_);

  gemm_qkv<<<dim3(32, 8, 3), 256, 0, stream>>>(xb, wqb, wkb, wvb, bq, bv, Qb,
                                               Kb, Vb);
  attn_fwd<<<dim3(32, 32), 256, 0, stream>>>(Qb, Kb, Vb, Yb);
  gemm_out<<<dim3(32, 8), 256, 0, stream>>>(Yb, wob, bo, out);
}

// Round 2
// 132.387 us; speedup vs baseline: 2.1394x; 2.1394x over previous
//
#include <hip/hip_runtime.h>
#include <hip/hip_bf16.h>
#include <stdint.h>

#define B_ 2
#define T_ 2048
#define C_ 1024
#define H_ 16
#define D_ 64
#define M_ (B_ * T_)  // 4096

typedef __bf16 bf16x8 __attribute__((ext_vector_type(8)));
typedef float f32x4 __attribute__((ext_vector_type(4)));
typedef float f32x16 __attribute__((ext_vector_type(16)));

__device__ inline void gload_lds16(const void* g, void* l) {
  __builtin_amdgcn_global_load_lds(
      (const __attribute__((address_space(1))) void*)g,
      (__attribute__((address_space(3))) void*)l, 16, 0, 0);
}

// ---------------- fp32 -> bf16 convert ----------------
__global__ void cvt_f32_bf16(const float* __restrict__ in,
                             __hip_bfloat16* __restrict__ out, int n) {
  int i = (blockIdx.x * blockDim.x + threadIdx.x) * 4;
  int stride = gridDim.x * blockDim.x * 4;
  for (; i < n; i += stride) {
    float4 v = *(const float4*)(in + i);
    union { __hip_bfloat16 h[4]; ushort4 u; } cv;
    cv.h[0] = __float2bfloat16(v.x);
    cv.h[1] = __float2bfloat16(v.y);
    cv.h[2] = __float2bfloat16(v.z);
    cv.h[3] = __float2bfloat16(v.w);
    *(ushort4*)(out + i) = cv.u;
  }
}

// ---------------- QKV projection GEMM ----------------
// z=0: Q[m=t][n=c] -> [B,H,T,D]; z=1: K same; z=2: operand-swapped ->
// VT[m=c][n=t] -> [B,H,D,T] (V transposed for attention's PV B-operand).
__global__ __launch_bounds__(256) void gemm_qkv(
    const __hip_bfloat16* __restrict__ X,
    const __hip_bfloat16* __restrict__ Wq,
    const __hip_bfloat16* __restrict__ Wk,
    const __hip_bfloat16* __restrict__ Wv,
    const float* __restrict__ bq, const float* __restrict__ bv,
    __hip_bfloat16* __restrict__ Qo, __hip_bfloat16* __restrict__ Ko,
    __hip_bfloat16* __restrict__ VTo) {
  const int z = blockIdx.z;
  const __hip_bfloat16* Amat;
  const __hip_bfloat16* Bmat;
  int bm, bn;
  if (z == 2) {
    Amat = Wv; Bmat = X; bm = blockIdx.y; bn = blockIdx.x;
  } else {
    Amat = X; Bmat = (z == 0) ? Wq : Wk; bm = blockIdx.x; bn = blockIdx.y;
  }

  const int tid = threadIdx.x;
  const int w = tid >> 6, lane = tid & 63;
  const int wr = w >> 1, wc = w & 1;
  const int lrow = lane & 15, lk = (lane >> 4) * 8;

  __shared__ __hip_bfloat16 As[128 * 32];
  __shared__ __hip_bfloat16 Bs[128 * 32];

  f32x4 acc[4][4];
#pragma unroll
  for (int m = 0; m < 4; ++m)
#pragma unroll
    for (int n = 0; n < 4; ++n) acc[m][n] = (f32x4){0.f, 0.f, 0.f, 0.f};

  for (int k0 = 0; k0 < C_; k0 += 32) {
#pragma unroll
    for (int it = 0; it < 2; ++it) {
      int e = it * 2048 + w * 512 + lane * 8;
      int row = e >> 5, col = e & 31;
      gload_lds16(Amat + (size_t)(bm * 128 + row) * C_ + k0 + col, &As[e]);
      gload_lds16(Bmat + (size_t)(bn * 128 + row) * C_ + k0 + col, &Bs[e]);
    }
    asm volatile("s_waitcnt vmcnt(0)" ::: "memory");
    __syncthreads();

    bf16x8 af[4], bfr[4];
#pragma unroll
    for (int m = 0; m < 4; ++m)
      af[m] = *(const bf16x8*)&As[(wr * 64 + m * 16 + lrow) * 32 + lk];
#pragma unroll
    for (int n = 0; n < 4; ++n)
      bfr[n] = *(const bf16x8*)&Bs[(wc * 64 + n * 16 + lrow) * 32 + lk];
#pragma unroll
    for (int m = 0; m < 4; ++m)
#pragma unroll
      for (int n = 0; n < 4; ++n)
        acc[m][n] = __builtin_amdgcn_mfma_f32_16x16x32_bf16(af[m], bfr[n],
                                                            acc[m][n], 0, 0, 0);
    __syncthreads();
  }

#pragma unroll
  for (int m = 0; m < 4; ++m) {
#pragma unroll
    for (int n = 0; n < 4; ++n) {
      f32x4 v = acc[m][n];
      int rowm = bm * 128 + wr * 64 + m * 16 + (lane >> 4) * 4;
      int coln = bn * 128 + wc * 64 + n * 16 + (lane & 15);
      if (z == 2) {
        // rows = c, cols = t; bias bv along rows; out VT [B,H,D,T]
        int b = coln >> 11, tl = coln & 2047;
#pragma unroll
        for (int r = 0; r < 4; ++r) {
          int rc = rowm + r;
          int h = rc >> 6, d = rc & 63;
          VTo[(((size_t)(b * H_ + h)) * D_ + d) * T_ + tl] =
              __float2bfloat16(v[r] + bv[rc]);
        }
      } else {
        float bb = (z == 0) ? bq[coln] : 0.f;
        int h = coln >> 6, d = coln & 63;
        __hip_bfloat16* Out = (z == 0) ? Qo : Ko;
#pragma unroll
        for (int r = 0; r < 4; ++r) {
          int row = rowm + r;
          int b = row >> 11, t = row & 2047;
          Out[(((size_t)(b * H_ + h)) * T_ + t) * D_ + d] =
              __float2bfloat16(v[r] + bb);
        }
      }
    }
  }
}

// ---------------- output projection GEMM (fp32 out) ----------------
__global__ __launch_bounds__(256) void gemm_out(
    const __hip_bfloat16* __restrict__ X,
    const __hip_bfloat16* __restrict__ W,
    const float* __restrict__ bias, float* __restrict__ Out) {
  const int bm = blockIdx.x, bn = blockIdx.y;
  const int tid = threadIdx.x;
  const int w = tid >> 6, lane = tid & 63;
  const int wr = w >> 1, wc = w & 1;
  const int lrow = lane & 15, lk = (lane >> 4) * 8;

  __shared__ __hip_bfloat16 As[128 * 32];
  __shared__ __hip_bfloat16 Bs[128 * 32];

  f32x4 acc[4][4];
#pragma unroll
  for (int m = 0; m < 4; ++m)
#pragma unroll
    for (int n = 0; n < 4; ++n) acc[m][n] = (f32x4){0.f, 0.f, 0.f, 0.f};

  for (int k0 = 0; k0 < C_; k0 += 32) {
#pragma unroll
    for (int it = 0; it < 2; ++it) {
      int e = it * 2048 + w * 512 + lane * 8;
      int row = e >> 5, col = e & 31;
      gload_lds16(X + (size_t)(bm * 128 + row) * C_ + k0 + col, &As[e]);
      gload_lds16(W + (size_t)(bn * 128 + row) * C_ + k0 + col, &Bs[e]);
    }
    asm volatile("s_waitcnt vmcnt(0)" ::: "memory");
    __syncthreads();

    bf16x8 af[4], bfr[4];
#pragma unroll
    for (int m = 0; m < 4; ++m)
      af[m] = *(const bf16x8*)&As[(wr * 64 + m * 16 + lrow) * 32 + lk];
#pragma unroll
    for (int n = 0; n < 4; ++n)
      bfr[n] = *(const bf16x8*)&Bs[(wc * 64 + n * 16 + lrow) * 32 + lk];
#pragma unroll
    for (int m = 0; m < 4; ++m)
#pragma unroll
      for (int n = 0; n < 4; ++n)
        acc[m][n] = __builtin_amdgcn_mfma_f32_16x16x32_bf16(af[m], bfr[n],
                                                            acc[m][n], 0, 0, 0);
    __syncthreads();
  }

#pragma unroll
  for (int m = 0; m < 4; ++m) {
#pragma unroll
    for (int n = 0; n < 4; ++n) {
      f32x4 v = acc[m][n];
      int coln = bn * 128 + wc * 64 + n * 16 + (lane & 15);
      float bb = bias[coln];
#pragma unroll
      for (int r = 0; r < 4; ++r) {
        int row = bm * 128 + wr * 64 + m * 16 + (lane >> 4) * 4 + r;
        Out[(size_t)row * C_ + coln] = v[r] + bb;
      }
    }
  }
}

// ---------------- flash attention (causal), swapped-operand 32x32 ----------
// grid (16, 32): x -> q-tile (descending for LPT), y -> bh. 8 waves:
// group g = wid>>2 handles kv64 tiles {2s+g}; warp wq owns 32 q-rows.
#define SCALE_ 0.125f
#define MASKV_ -1e30f
#define MFLOOR_ -30000.0f

__global__ __launch_bounds__(512, 4) void attn_fwd(
    const __hip_bfloat16* __restrict__ Q, const __hip_bfloat16* __restrict__ K,
    const __hip_bfloat16* __restrict__ VT, __hip_bfloat16* __restrict__ Y) {
  const int qt = (gridDim.x - 1) - blockIdx.x;
  const int bh = blockIdx.y;
  const int tid = threadIdx.x;
  const int wid = tid >> 6, lane = tid & 63;
  const int g = wid >> 2, wq = wid & 3;
  const int hi = lane >> 5, q32 = lane & 31;
  const size_t base = (size_t)bh * T_ * D_;

  __shared__ __hip_bfloat16 Ks[2][64][64];
  __shared__ __hip_bfloat16 Vts[2][64][64];
  __shared__ float Sml[2][4][2][32];
  __shared__ float Om[4][32][68];

  const int qg = qt * 128 + wq * 32 + q32;

  bf16x8 qf[4];
#pragma unroll
  for (int dk = 0; dk < 4; ++dk)
    qf[dk] = *(const bf16x8*)&Q[base + (size_t)qg * D_ + dk * 16 + hi * 8];

  f32x16 o0 = {}, o1 = {};
  float m_run = MFLOOR_, l_run = 0.f;

  const int gt = tid & 255;
  const int srow = gt >> 3, scnk = gt & 7;
  const int swz = (scnk ^ (srow & 7)) * 8;  // pre-swizzled source chunk

  for (int s = 0; s <= qt; ++s) {
    const int kt = 2 * s + g;
    // stage K and VT tiles (linear LDS dest, swizzle folded into global src)
#pragma unroll
    for (int h2 = 0; h2 < 2; ++h2) {
      int row = srow + 32 * h2;
      gload_lds16(K + base + (size_t)(kt * 64 + row) * D_ + swz,
                  &Ks[g][row][scnk * 8]);
      gload_lds16(VT + base + (size_t)row * T_ + kt * 64 + swz,
                  &Vts[g][row][scnk * 8]);
    }
    asm volatile("s_waitcnt vmcnt(0)" ::: "memory");
    __syncthreads();

    // QK^T swapped: st = mfma(K-rows, Q-rows): lane owns q=lane&31
    f32x16 st0 = {}, st1 = {};
#pragma unroll
    for (int dk = 0; dk < 4; ++dk) {
      int off = (dk * 16 + hi * 8) ^ ((lane & 7) << 3);
      bf16x8 a0 = *(const bf16x8*)&Ks[g][q32][off];
      bf16x8 a1 = *(const bf16x8*)&Ks[g][q32 + 32][off];
      st0 = __builtin_amdgcn_mfma_f32_32x32x16_bf16(a0, qf[dk], st0, 0, 0, 0);
      st1 = __builtin_amdgcn_mfma_f32_32x32x16_bf16(a1, qf[dk], st1, 0, 0, 0);
    }

    float sc[32];
#pragma unroll
    for (int r = 0; r < 16; ++r) {
      sc[r] = st0[r] * SCALE_;
      sc[16 + r] = st1[r] * SCALE_;
    }
    if (s == qt) {  // diagonal tiles: causal mask
#pragma unroll
      for (int r = 0; r < 16; ++r) {
        int kvl = (r & 3) + 8 * (r >> 2) + 4 * hi;
        if (kt * 64 + kvl > qg) sc[r] = MASKV_;
        if (kt * 64 + 32 + kvl > qg) sc[16 + r] = MASKV_;
      }
    }
    float mt = sc[0];
#pragma unroll
    for (int r = 1; r < 32; ++r) mt = fmaxf(mt, sc[r]);
    mt = fmaxf(mt, __shfl_xor(mt, 32));
    float m_new = fmaxf(m_run, mt);
    float alpha = __expf(m_run - m_new);
    m_run = m_new;
    float ls = 0.f;
#pragma unroll
    for (int r = 0; r < 32; ++r) {
      float p = __expf(sc[r] - m_new);
      sc[r] = p;
      ls += p;
    }
    ls += __shfl_xor(ls, 32);
    l_run = l_run * alpha + ls;
#pragma unroll
    for (int r = 0; r < 16; ++r) {
      o0[r] *= alpha;
      o1[r] *= alpha;
    }

    // pack P to bf16 B-fragments (cvt_pk + permlane32_swap) and PV
#pragma unroll
    for (int ks = 0; ks < 4; ++ks) {
      union { unsigned w[4]; bf16x8 v; } pa;
      unsigned A, Bb;
      asm("v_cvt_pk_bf16_f32 %0, %1, %2"
          : "=v"(A) : "v"(sc[ks * 8 + 0]), "v"(sc[ks * 8 + 1]));
      asm("v_cvt_pk_bf16_f32 %0, %1, %2"
          : "=v"(Bb) : "v"(sc[ks * 8 + 4]), "v"(sc[ks * 8 + 5]));
      asm volatile("v_permlane32_swap_b32 %0, %1" : "+v"(A), "+v"(Bb));
      pa.w[0] = A;
      pa.w[2] = Bb;
      asm("v_cvt_pk_bf16_f32 %0, %1, %2"
          : "=v"(A) : "v"(sc[ks * 8 + 2]), "v"(sc[ks * 8 + 3]));
      asm("v_cvt_pk_bf16_f32 %0, %1, %2"
          : "=v"(Bb) : "v"(sc[ks * 8 + 6]), "v"(sc[ks * 8 + 7]));
      asm volatile("v_permlane32_swap_b32 %0, %1" : "+v"(A), "+v"(Bb));
      pa.w[1] = A;
      pa.w[3] = Bb;

      int voff = (ks * 16 + hi * 8) ^ ((lane & 7) << 3);
      bf16x8 v0 = *(const bf16x8*)&Vts[g][q32][voff];
      bf16x8 v1 = *(const bf16x8*)&Vts[g][q32 + 32][voff];
      o0 = __builtin_amdgcn_mfma_f32_32x32x16_bf16(v0, pa.v, o0, 0, 0, 0);
      o1 = __builtin_amdgcn_mfma_f32_32x32x16_bf16(v1, pa.v, o1, 0, 0, 0);
    }
    __syncthreads();
  }

  // merge the two kv-split groups
  if (lane < 32) {
    Sml[g][wq][0][lane] = m_run;
    Sml[g][wq][1][lane] = l_run;
  }
  __syncthreads();
  float mo = Sml[1 - g][wq][0][q32];
  float lo_ = Sml[1 - g][wq][1][q32];
  float mstar = fmaxf(m_run, mo);
  float f = __expf(m_run - mstar);
  float fo = __expf(mo - mstar);
  float lstar = l_run * f + lo_ * fo;

  if (g == 1) {
#pragma unroll
    for (int dt = 0; dt < 2; ++dt) {
#pragma unroll
      for (int grp = 0; grp < 4; ++grp) {
        int dbase = grp * 8 + hi * 4 + dt * 32;
        float4 t4;
        t4.x = (dt ? o1[grp * 4 + 0] : o0[grp * 4 + 0]) * f;
        t4.y = (dt ? o1[grp * 4 + 1] : o0[grp * 4 + 1]) * f;
        t4.z = (dt ? o1[grp * 4 + 2] : o0[grp * 4 + 2]) * f;
        t4.w = (dt ? o1[grp * 4 + 3] : o0[grp * 4 + 3]) * f;
        *(float4*)&Om[wq][q32][dbase] = t4;
      }
    }
  }
  __syncthreads();
  if (g == 0) {
    float inv = 1.0f / lstar;
    const int b = bh >> 4, hh = bh & 15;
#pragma unroll
    for (int dt = 0; dt < 2; ++dt) {
#pragma unroll
      for (int grp = 0; grp < 4; ++grp) {
        int dbase = grp * 8 + hi * 4 + dt * 32;
        float4 m4 = *(float4*)&Om[wq][q32][dbase];
        union { __hip_bfloat16 h4[4]; ushort4 u; } pk;
        float e0 = (dt ? o1[grp * 4 + 0] : o0[grp * 4 + 0]) * f + m4.x;
        float e1 = (dt ? o1[grp * 4 + 1] : o0[grp * 4 + 1]) * f + m4.y;
        float e2 = (dt ? o1[grp * 4 + 2] : o0[grp * 4 + 2]) * f + m4.z;
        float e3 = (dt ? o1[grp * 4 + 3] : o0[grp * 4 + 3]) * f + m4.w;
        pk.h4[0] = __float2bfloat16(e0 * inv);
        pk.h4[1] = __float2bfloat16(e1 * inv);
        pk.h4[2] = __float2bfloat16(e2 * inv);
        pk.h4[3] = __float2bfloat16(e3 * inv);
        *(ushort4*)&Y[((size_t)b * T_ + qg) * C_ + hh * 64 + dbase] = pk.u;
      }
    }
  }
}

extern "C" void kernel_launch(void* const* d_in, const int* in_sizes, int n_in,
                              void* d_out, int out_size, void* d_ws,
                              size_t ws_size, hipStream_t stream) {
  const float* x = (const float*)d_in[0];
  const float* Wk = (const float*)d_in[1];
  const float* Wq = (const float*)d_in[2];
  const float* bq = (const float*)d_in[3];
  const float* Wv = (const float*)d_in[4];
  const float* bv = (const float*)d_in[5];
  const float* Wo = (const float*)d_in[6];
  const float* bo = (const float*)d_in[7];
  float* out = (float*)d_out;

  char* ws = (char*)d_ws;
  __hip_bfloat16* xb = (__hip_bfloat16*)(ws);
  __hip_bfloat16* wqb = (__hip_bfloat16*)(ws + (8ull << 20));
  __hip_bfloat16* wkb = (__hip_bfloat16*)(ws + (10ull << 20));
  __hip_bfloat16* wvb = (__hip_bfloat16*)(ws + (12ull << 20));
  __hip_bfloat16* wob = (__hip_bfloat16*)(ws + (14ull << 20));
  __hip_bfloat16* Qb = (__hip_bfloat16*)(ws + (16ull << 20));
  __hip_bfloat16* Kb = (__hip_bfloat16*)(ws + (24ull << 20));
  __hip_bfloat16* VTb = (__hip_bfloat16*)(ws + (32ull << 20));
  __hip_bfloat16* Yb = (__hip_bfloat16*)(ws + (40ull << 20));

  cvt_f32_bf16<<<1024, 256, 0, stream>>>(x, xb, M_ * C_);
  cvt_f32_bf16<<<512, 256, 0, stream>>>(Wq, wqb, C_ * C_);
  cvt_f32_bf16<<<512, 256, 0, stream>>>(Wk, wkb, C_ * C_);
  cvt_f32_bf16<<<512, 256, 0, stream>>>(Wv, wvb, C_ * C_);
  cvt_f32_bf16<<<512, 256, 0, stream>>>(Wo, wob, C_ * C_);

  gemm_qkv<<<dim3(32, 8, 3), 256, 0, stream>>>(xb, wqb, wkb, wvb, bq, bv, Qb,
                                               Kb, VTb);
  attn_fwd<<<dim3(16, 32), 512, 0, stream>>>(Qb, Kb, VTb, Yb);
  gemm_out<<<dim3(32, 8), 256, 0, stream>>>(Yb, wob, bo, out);
}

// Round 4
// 118.637 us; speedup vs baseline: 2.3873x; 1.1159x over previous
//
#include <hip/hip_runtime.h>
#include <hip/hip_bf16.h>
#include <stdint.h>

#define B_ 2
#define T_ 2048
#define C_ 1024
#define H_ 16
#define D_ 64
#define M_ (B_ * T_)  // 4096

typedef __bf16 bf16x8 __attribute__((ext_vector_type(8)));
typedef float f32x4 __attribute__((ext_vector_type(4)));
typedef float f32x16 __attribute__((ext_vector_type(16)));

__device__ inline void gload_lds16(const void* g, void* l) {
  __builtin_amdgcn_global_load_lds(
      (const __attribute__((address_space(1))) void*)g,
      (__attribute__((address_space(3))) void*)l, 16, 0, 0);
}

// ---------------- fused fp32 -> bf16 convert (1 launch) ----------------
__global__ __launch_bounds__(256) void cvt_all(
    const float* __restrict__ x, const float* __restrict__ Wq,
    const float* __restrict__ Wk, const float* __restrict__ Wv,
    const float* __restrict__ Wo, __hip_bfloat16* __restrict__ xb,
    __hip_bfloat16* __restrict__ wqb, __hip_bfloat16* __restrict__ wkb,
    __hip_bfloat16* __restrict__ wvb, __hip_bfloat16* __restrict__ wob) {
  size_t t = (size_t)blockIdx.x * 256 + threadIdx.x;
  size_t e = t * 4;
  const float* src;
  __hip_bfloat16* dst;
  size_t off;
  if (e < 4194304) {
    src = x; dst = xb; off = e;
  } else {
    size_t u = e - 4194304;
    int seg = (int)(u >> 20);
    off = u & 1048575;
    src = (seg == 0) ? Wq : (seg == 1) ? Wk : (seg == 2) ? Wv : Wo;
    dst = (seg == 0) ? wqb : (seg == 1) ? wkb : (seg == 2) ? wvb : wob;
  }
  float4 v = *(const float4*)(src + off);
  union { __hip_bfloat16 h[4]; ushort4 u4; } cv;
  cv.h[0] = __float2bfloat16(v.x);
  cv.h[1] = __float2bfloat16(v.y);
  cv.h[2] = __float2bfloat16(v.z);
  cv.h[3] = __float2bfloat16(v.w);
  *(ushort4*)(dst + off) = cv.u4;
}

// ---------------- QKV projection GEMM ----------------
// z=0: Q (pre-scaled by 1/8) -> [B,H,T,D]; z=1: K same layout; z=2:
// operand-swapped -> VT [B,H,D,T].
__global__ __launch_bounds__(256) void gemm_qkv(
    const __hip_bfloat16* __restrict__ X,
    const __hip_bfloat16* __restrict__ Wq,
    const __hip_bfloat16* __restrict__ Wk,
    const __hip_bfloat16* __restrict__ Wv,
    const float* __restrict__ bq, const float* __restrict__ bv,
    __hip_bfloat16* __restrict__ Qo, __hip_bfloat16* __restrict__ Ko,
    __hip_bfloat16* __restrict__ VTo) {
  const int z = blockIdx.z;
  const int bx = ((blockIdx.x & 3) << 3) | (blockIdx.x >> 2);  // XCD cluster
  const __hip_bfloat16* Amat;
  const __hip_bfloat16* Bmat;
  int bm, bn;
  if (z == 2) {
    Amat = Wv; Bmat = X; bm = blockIdx.y; bn = bx;
  } else {
    Amat = X; Bmat = (z == 0) ? Wq : Wk; bm = bx; bn = blockIdx.y;
  }

  const int tid = threadIdx.x;
  const int w = tid >> 6, lane = tid & 63;
  const int wr = w >> 1, wc = w & 1;
  const int lrow = lane & 15, lk = (lane >> 4) * 8;

  __shared__ __hip_bfloat16 As[128 * 32];
  __shared__ __hip_bfloat16 Bs[128 * 32];

  f32x4 acc[4][4];
#pragma unroll
  for (int m = 0; m < 4; ++m)
#pragma unroll
    for (int n = 0; n < 4; ++n) acc[m][n] = (f32x4){0.f, 0.f, 0.f, 0.f};

  for (int k0 = 0; k0 < C_; k0 += 32) {
#pragma unroll
    for (int it = 0; it < 2; ++it) {
      int e = it * 2048 + w * 512 + lane * 8;
      int row = e >> 5, col = e & 31;
      gload_lds16(Amat + (size_t)(bm * 128 + row) * C_ + k0 + col, &As[e]);
      gload_lds16(Bmat + (size_t)(bn * 128 + row) * C_ + k0 + col, &Bs[e]);
    }
    asm volatile("s_waitcnt vmcnt(0)" ::: "memory");
    __syncthreads();

    bf16x8 af[4], bfr[4];
#pragma unroll
    for (int m = 0; m < 4; ++m)
      af[m] = *(const bf16x8*)&As[(wr * 64 + m * 16 + lrow) * 32 + lk];
#pragma unroll
    for (int n = 0; n < 4; ++n)
      bfr[n] = *(const bf16x8*)&Bs[(wc * 64 + n * 16 + lrow) * 32 + lk];
#pragma unroll
    for (int m = 0; m < 4; ++m)
#pragma unroll
      for (int n = 0; n < 4; ++n)
        acc[m][n] = __builtin_amdgcn_mfma_f32_16x16x32_bf16(af[m], bfr[n],
                                                            acc[m][n], 0, 0, 0);
    __syncthreads();
  }

#pragma unroll
  for (int m = 0; m < 4; ++m) {
#pragma unroll
    for (int n = 0; n < 4; ++n) {
      f32x4 v = acc[m][n];
      int rowm = bm * 128 + wr * 64 + m * 16 + (lane >> 4) * 4;
      int coln = bn * 128 + wc * 64 + n * 16 + (lane & 15);
      if (z == 2) {
        int b = coln >> 11, tl = coln & 2047;
#pragma unroll
        for (int r = 0; r < 4; ++r) {
          int rc = rowm + r;
          int h = rc >> 6, d = rc & 63;
          VTo[(((size_t)(b * H_ + h)) * D_ + d) * T_ + tl] =
              __float2bfloat16(v[r] + bv[rc]);
        }
      } else {
        float bb = (z == 0) ? bq[coln] : 0.f;
        float sc = (z == 0) ? 0.125f : 1.0f;  // Q pre-scaled by D^-0.5
        int h = coln >> 6, d = coln & 63;
        __hip_bfloat16* Out = (z == 0) ? Qo : Ko;
#pragma unroll
        for (int r = 0; r < 4; ++r) {
          int row = rowm + r;
          int b = row >> 11, t = row & 2047;
          Out[(((size_t)(b * H_ + h)) * T_ + t) * D_ + d] =
              __float2bfloat16((v[r] + bb) * sc);
        }
      }
    }
  }
}

// ---------------- output projection GEMM (fp32 out) ----------------
__global__ __launch_bounds__(256) void gemm_out(
    const __hip_bfloat16* __restrict__ X,
    const __hip_bfloat16* __restrict__ W,
    const float* __restrict__ bias, float* __restrict__ Out) {
  const int bm = ((blockIdx.x & 3) << 3) | (blockIdx.x >> 2);
  const int bn = blockIdx.y;
  const int tid = threadIdx.x;
  const int w = tid >> 6, lane = tid & 63;
  const int wr = w >> 1, wc = w & 1;
  const int lrow = lane & 15, lk = (lane >> 4) * 8;

  __shared__ __hip_bfloat16 As[128 * 32];
  __shared__ __hip_bfloat16 Bs[128 * 32];

  f32x4 acc[4][4];
#pragma unroll
  for (int m = 0; m < 4; ++m)
#pragma unroll
    for (int n = 0; n < 4; ++n) acc[m][n] = (f32x4){0.f, 0.f, 0.f, 0.f};

  for (int k0 = 0; k0 < C_; k0 += 32) {
#pragma unroll
    for (int it = 0; it < 2; ++it) {
      int e = it * 2048 + w * 512 + lane * 8;
      int row = e >> 5, col = e & 31;
      gload_lds16(X + (size_t)(bm * 128 + row) * C_ + k0 + col, &As[e]);
      gload_lds16(W + (size_t)(bn * 128 + row) * C_ + k0 + col, &Bs[e]);
    }
    asm volatile("s_waitcnt vmcnt(0)" ::: "memory");
    __syncthreads();

    bf16x8 af[4], bfr[4];
#pragma unroll
    for (int m = 0; m < 4; ++m)
      af[m] = *(const bf16x8*)&As[(wr * 64 + m * 16 + lrow) * 32 + lk];
#pragma unroll
    for (int n = 0; n < 4; ++n)
      bfr[n] = *(const bf16x8*)&Bs[(wc * 64 + n * 16 + lrow) * 32 + lk];
#pragma unroll
    for (int m = 0; m < 4; ++m)
#pragma unroll
      for (int n = 0; n < 4; ++n)
        acc[m][n] = __builtin_amdgcn_mfma_f32_16x16x32_bf16(af[m], bfr[n],
                                                            acc[m][n], 0, 0, 0);
    __syncthreads();
  }

#pragma unroll
  for (int m = 0; m < 4; ++m) {
#pragma unroll
    for (int n = 0; n < 4; ++n) {
      f32x4 v = acc[m][n];
      int coln = bn * 128 + wc * 64 + n * 16 + (lane & 15);
      float bb = bias[coln];
#pragma unroll
      for (int r = 0; r < 4; ++r) {
        int row = bm * 128 + wr * 64 + m * 16 + (lane >> 4) * 4 + r;
        Out[(size_t)row * C_ + coln] = v[r] + bb;
      }
    }
  }
}

// ---------------- flash attention (causal), swapped 32x32, pipelined -------
#define MASKV_ -1e30f
#define MFLOOR_ -30000.0f
#define THR_ 8.0f

__global__ __launch_bounds__(512, 4) void attn_fwd(
    const __hip_bfloat16* __restrict__ Q, const __hip_bfloat16* __restrict__ K,
    const __hip_bfloat16* __restrict__ VT, __hip_bfloat16* __restrict__ Y) {
  const int qt = (gridDim.x - 1) - blockIdx.x;
  const int bh = blockIdx.y;
  const int tid = threadIdx.x;
  const int wid = tid >> 6, lane = tid & 63;
  const int g = wid >> 2, wq = wid & 3;
  const int hi = lane >> 5, q32 = lane & 31;
  const size_t base = (size_t)bh * T_ * D_;

  // LDS: K bufs [g][dbuf] 32KB | VT bufs 32KB | Sml 2KB. Om aliases K/V.
  __shared__ __align__(16) char smem[65536 + 2048];
  auto KsP = (__hip_bfloat16(*)[64][64])(smem);           // [g*2+buf]
  auto VtsP = (__hip_bfloat16(*)[64][64])(smem + 32768);  // [g*2+buf]
  float* Sml = (float*)(smem + 65536);                    // [g][wq][2][32]
  float(*Om)[32][68] = (float(*)[32][68])(smem);          // alias (post-loop)

  const int qg = qt * 128 + wq * 32 + q32;

  bf16x8 qf[4];
#pragma unroll
  for (int dk = 0; dk < 4; ++dk)
    qf[dk] = *(const bf16x8*)&Q[base + (size_t)qg * D_ + dk * 16 + hi * 8];

  f32x16 o0 = {}, o1 = {};
  float m_run = MFLOOR_, l_run = 0.f;

  const int gt = tid & 255;
  const int srow = gt >> 3, scnk = gt & 7;
  const int swz = (scnk ^ (srow & 7)) * 8;  // pre-swizzled source chunk

#define STAGE(buf, kt)                                                      \
  {                                                                         \
    _Pragma("unroll") for (int h2 = 0; h2 < 2; ++h2) {                      \
      int row = srow + 32 * h2;                                             \
      gload_lds16(K + base + (size_t)((kt)*64 + row) * D_ + swz,            \
                  &KsP[g * 2 + (buf)][row][scnk * 8]);                      \
      gload_lds16(VT + base + (size_t)row * T_ + (kt)*64 + swz,             \
                  &VtsP[g * 2 + (buf)][row][scnk * 8]);                     \
    }                                                                       \
  }

  // prologue: stage tile s=0
  STAGE(0, g);
  asm volatile("s_waitcnt vmcnt(0)" ::: "memory");
  __syncthreads();

  int cur = 0;
  for (int s = 0; s <= qt; ++s) {
    const int kt = 2 * s + g;
    if (s < qt) STAGE(cur ^ 1, 2 * (s + 1) + g);  // prefetch next (hidden)

    // QK^T swapped: lane owns q=lane&31
    f32x16 st0 = {}, st1 = {};
    __builtin_amdgcn_s_setprio(1);
#pragma unroll
    for (int dk = 0; dk < 4; ++dk) {
      int off = (dk * 16 + hi * 8) ^ ((lane & 7) << 3);
      bf16x8 a0 = *(const bf16x8*)&KsP[g * 2 + cur][q32][off];
      bf16x8 a1 = *(const bf16x8*)&KsP[g * 2 + cur][q32 + 32][off];
      st0 = __builtin_amdgcn_mfma_f32_32x32x16_bf16(a0, qf[dk], st0, 0, 0, 0);
      st1 = __builtin_amdgcn_mfma_f32_32x32x16_bf16(a1, qf[dk], st1, 0, 0, 0);
    }
    __builtin_amdgcn_s_setprio(0);

    float sc[32];
#pragma unroll
    for (int r = 0; r < 16; ++r) {
      sc[r] = st0[r];
      sc[16 + r] = st1[r];
    }
    if (s == qt) {  // diagonal: causal mask
#pragma unroll
      for (int r = 0; r < 16; ++r) {
        int kvl = (r & 3) + 8 * (r >> 2) + 4 * hi;
        if (kt * 64 + kvl > qg) sc[r] = MASKV_;
        if (kt * 64 + 32 + kvl > qg) sc[16 + r] = MASKV_;
      }
    }
    float mt = sc[0];
#pragma unroll
    for (int r = 1; r < 32; ++r) mt = fmaxf(mt, sc[r]);
    mt = fmaxf(mt, __shfl_xor(mt, 32));
    if (__any(mt - m_run > THR_)) {  // defer-max (T13)
      float m_new = fmaxf(m_run, mt);
      float alpha = __expf(m_run - m_new);
      m_run = m_new;
      l_run *= alpha;
#pragma unroll
      for (int r = 0; r < 16; ++r) {
        o0[r] *= alpha;
        o1[r] *= alpha;
      }
    }
    float ls = 0.f;
#pragma unroll
    for (int r = 0; r < 32; ++r) {
      float p = __expf(sc[r] - m_run);
      sc[r] = p;
      ls += p;
    }
    ls += __shfl_xor(ls, 32);
    l_run += ls;

    // pack P to bf16 B-fragments (cvt_pk + permlane32_swap) and PV
    __builtin_amdgcn_s_setprio(1);
#pragma unroll
    for (int ks = 0; ks < 4; ++ks) {
      union { unsigned w[4]; bf16x8 v; } pa;
      unsigned A, Bb;
      asm("v_cvt_pk_bf16_f32 %0, %1, %2"
          : "=v"(A) : "v"(sc[ks * 8 + 0]), "v"(sc[ks * 8 + 1]));
      asm("v_cvt_pk_bf16_f32 %0, %1, %2"
          : "=v"(Bb) : "v"(sc[ks * 8 + 4]), "v"(sc[ks * 8 + 5]));
      asm volatile("v_permlane32_swap_b32 %0, %1" : "+v"(A), "+v"(Bb));
      pa.w[0] = A;
      pa.w[2] = Bb;
      asm("v_cvt_pk_bf16_f32 %0, %1, %2"
          : "=v"(A) : "v"(sc[ks * 8 + 2]), "v"(sc[ks * 8 + 3]));
      asm("v_cvt_pk_bf16_f32 %0, %1, %2"
          : "=v"(Bb) : "v"(sc[ks * 8 + 6]), "v"(sc[ks * 8 + 7]));
      asm volatile("v_permlane32_swap_b32 %0, %1" : "+v"(A), "+v"(Bb));
      pa.w[1] = A;
      pa.w[3] = Bb;

      int voff = (ks * 16 + hi * 8) ^ ((lane & 7) << 3);
      bf16x8 v0 = *(const bf16x8*)&VtsP[g * 2 + cur][q32][voff];
      bf16x8 v1 = *(const bf16x8*)&VtsP[g * 2 + cur][q32 + 32][voff];
      o0 = __builtin_amdgcn_mfma_f32_32x32x16_bf16(v0, pa.v, o0, 0, 0, 0);
      o1 = __builtin_amdgcn_mfma_f32_32x32x16_bf16(v1, pa.v, o1, 0, 0, 0);
    }
    __builtin_amdgcn_s_setprio(0);

    asm volatile("s_waitcnt vmcnt(0)" ::: "memory");  // next tile landed
    __syncthreads();
    cur ^= 1;
  }

  // merge the two kv-split groups (Om aliases K/V region — loop is done)
  if (lane < 32) {
    Sml[((g * 4 + wq) * 2 + 0) * 32 + lane] = m_run;
    Sml[((g * 4 + wq) * 2 + 1) * 32 + lane] = l_run;
  }
  __syncthreads();
  float mo = Sml[(((1 - g) * 4 + wq) * 2 + 0) * 32 + q32];
  float lo_ = Sml[(((1 - g) * 4 + wq) * 2 + 1) * 32 + q32];
  float mstar = fmaxf(m_run, mo);
  float f = __expf(m_run - mstar);
  float fo = __expf(mo - mstar);
  float lstar = l_run * f + lo_ * fo;

  if (g == 1) {
#pragma unroll
    for (int dt = 0; dt < 2; ++dt) {
#pragma unroll
      for (int grp = 0; grp < 4; ++grp) {
        int dbase = grp * 8 + hi * 4 + dt * 32;
        float4 t4;
        t4.x = (dt ? o1[grp * 4 + 0] : o0[grp * 4 + 0]) * f;
        t4.y = (dt ? o1[grp * 4 + 1] : o0[grp * 4 + 1]) * f;
        t4.z = (dt ? o1[grp * 4 + 2] : o0[grp * 4 + 2]) * f;
        t4.w = (dt ? o1[grp * 4 + 3] : o0[grp * 4 + 3]) * f;
        *(float4*)&Om[wq][q32][dbase] = t4;
      }
    }
  }
  __syncthreads();
  if (g == 0) {
    float inv = 1.0f / lstar;
    const int b = bh >> 4, hh = bh & 15;
#pragma unroll
    for (int dt = 0; dt < 2; ++dt) {
#pragma unroll
      for (int grp = 0; grp < 4; ++grp) {
        int dbase = grp * 8 + hi * 4 + dt * 32;
        float4 m4 = *(float4*)&Om[wq][q32][dbase];
        union { __hip_bfloat16 h4[4]; ushort4 u; } pk;
        float e0 = (dt ? o1[grp * 4 + 0] : o0[grp * 4 + 0]) * f + m4.x;
        float e1 = (dt ? o1[grp * 4 + 1] : o0[grp * 4 + 1]) * f + m4.y;
        float e2 = (dt ? o1[grp * 4 + 2] : o0[grp * 4 + 2]) * f + m4.z;
        float e3 = (dt ? o1[grp * 4 + 3] : o0[grp * 4 + 3]) * f + m4.w;
        pk.h4[0] = __float2bfloat16(e0 * inv);
        pk.h4[1] = __float2bfloat16(e1 * inv);
        pk.h4[2] = __float2bfloat16(e2 * inv);
        pk.h4[3] = __float2bfloat16(e3 * inv);
        *(ushort4*)&Y[((size_t)b * T_ + qg) * C_ + hh * 64 + dbase] = pk.u;
      }
    }
  }
}

extern "C" void kernel_launch(void* const* d_in, const int* in_sizes, int n_in,
                              void* d_out, int out_size, void* d_ws,
                              size_t ws_size, hipStream_t stream) {
  const float* x = (const float*)d_in[0];
  const float* Wk = (const float*)d_in[1];
  const float* Wq = (const float*)d_in[2];
  const float* bq = (const float*)d_in[3];
  const float* Wv = (const float*)d_in[4];
  const float* bv = (const float*)d_in[5];
  const float* Wo = (const float*)d_in[6];
  const float* bo = (const float*)d_in[7];
  float* out = (float*)d_out;

  char* ws = (char*)d_ws;
  __hip_bfloat16* xb = (__hip_bfloat16*)(ws);
  __hip_bfloat16* wqb = (__hip_bfloat16*)(ws + (8ull << 20));
  __hip_bfloat16* wkb = (__hip_bfloat16*)(ws + (10ull << 20));
  __hip_bfloat16* wvb = (__hip_bfloat16*)(ws + (12ull << 20));
  __hip_bfloat16* wob = (__hip_bfloat16*)(ws + (14ull << 20));
  __hip_bfloat16* Qb = (__hip_bfloat16*)(ws + (16ull << 20));
  __hip_bfloat16* Kb = (__hip_bfloat16*)(ws + (24ull << 20));
  __hip_bfloat16* VTb = (__hip_bfloat16*)(ws + (32ull << 20));
  __hip_bfloat16* Yb = (__hip_bfloat16*)(ws + (40ull << 20));

  cvt_all<<<8192, 256, 0, stream>>>(x, Wq, Wk, Wv, Wo, xb, wqb, wkb, wvb, wob);
  gemm_qkv<<<dim3(32, 8, 3), 256, 0, stream>>>(xb, wqb, wkb, wvb, bq, bv, Qb,
                                               Kb, VTb);
  attn_fwd<<<dim3(16, 32), 512, 0, stream>>>(Qb, Kb, VTb, Yb);
  gemm_out<<<dim3(32, 8), 256, 0, stream>>>(Yb, wob, bo, out);
}

// Round 5
// 111.852 us; speedup vs baseline: 2.5321x; 1.0607x over previous
//
#include <hip/hip_runtime.h>
#include <hip/hip_bf16.h>
#include <stdint.h>

#define B_ 2
#define T_ 2048
#define C_ 1024
#define H_ 16
#define D_ 64
#define M_ (B_ * T_)  // 4096

typedef __bf16 bf16x8 __attribute__((ext_vector_type(8)));
typedef float f32x4 __attribute__((ext_vector_type(4)));
typedef float f32x16 __attribute__((ext_vector_type(16)));

__device__ inline void gload_lds16(const void* g, void* l) {
  __builtin_amdgcn_global_load_lds(
      (const __attribute__((address_space(1))) void*)g,
      (__attribute__((address_space(3))) void*)l, 16, 0, 0);
}

// ---------------- fused fp32 -> bf16 convert (1 launch) ----------------
__global__ __launch_bounds__(256) void cvt_all(
    const float* __restrict__ x, const float* __restrict__ Wq,
    const float* __restrict__ Wk, const float* __restrict__ Wv,
    const float* __restrict__ Wo, __hip_bfloat16* __restrict__ xb,
    __hip_bfloat16* __restrict__ wqb, __hip_bfloat16* __restrict__ wkb,
    __hip_bfloat16* __restrict__ wvb, __hip_bfloat16* __restrict__ wob) {
  size_t t = (size_t)blockIdx.x * 256 + threadIdx.x;
  size_t e = t * 4;
  const float* src;
  __hip_bfloat16* dst;
  size_t off;
  if (e < 4194304) {
    src = x; dst = xb; off = e;
  } else {
    size_t u = e - 4194304;
    int seg = (int)(u >> 20);
    off = u & 1048575;
    src = (seg == 0) ? Wq : (seg == 1) ? Wk : (seg == 2) ? Wv : Wo;
    dst = (seg == 0) ? wqb : (seg == 1) ? wkb : (seg == 2) ? wvb : wob;
  }
  float4 v = *(const float4*)(src + off);
  union { __hip_bfloat16 h[4]; ushort4 u4; } cv;
  cv.h[0] = __float2bfloat16(v.x);
  cv.h[1] = __float2bfloat16(v.y);
  cv.h[2] = __float2bfloat16(v.z);
  cv.h[3] = __float2bfloat16(v.w);
  *(ushort4*)(dst + off) = cv.u4;
}

// ---------------- QKV projection GEMM ----------------
// z=0: Q (pre-scaled by D^-0.5 * log2e for exp2-domain softmax) -> [B,H,T,D];
// z=1: K; z=2: operand-swapped -> VT [B,H,D,T].
__global__ __launch_bounds__(256) void gemm_qkv(
    const __hip_bfloat16* __restrict__ X,
    const __hip_bfloat16* __restrict__ Wq,
    const __hip_bfloat16* __restrict__ Wk,
    const __hip_bfloat16* __restrict__ Wv,
    const float* __restrict__ bq, const float* __restrict__ bv,
    __hip_bfloat16* __restrict__ Qo, __hip_bfloat16* __restrict__ Ko,
    __hip_bfloat16* __restrict__ VTo) {
  const int z = blockIdx.z;
  const int bx = ((blockIdx.x & 3) << 3) | (blockIdx.x >> 2);  // XCD cluster
  const __hip_bfloat16* Amat;
  const __hip_bfloat16* Bmat;
  int bm, bn;
  if (z == 2) {
    Amat = Wv; Bmat = X; bm = blockIdx.y; bn = bx;
  } else {
    Amat = X; Bmat = (z == 0) ? Wq : Wk; bm = bx; bn = blockIdx.y;
  }

  const int tid = threadIdx.x;
  const int w = tid >> 6, lane = tid & 63;
  const int wr = w >> 1, wc = w & 1;
  const int lrow = lane & 15, lk = (lane >> 4) * 8;

  __shared__ __hip_bfloat16 As[128 * 32];
  __shared__ __hip_bfloat16 Bs[128 * 32];

  f32x4 acc[4][4];
#pragma unroll
  for (int m = 0; m < 4; ++m)
#pragma unroll
    for (int n = 0; n < 4; ++n) acc[m][n] = (f32x4){0.f, 0.f, 0.f, 0.f};

  for (int k0 = 0; k0 < C_; k0 += 32) {
#pragma unroll
    for (int it = 0; it < 2; ++it) {
      int e = it * 2048 + w * 512 + lane * 8;
      int row = e >> 5, col = e & 31;
      gload_lds16(Amat + (size_t)(bm * 128 + row) * C_ + k0 + col, &As[e]);
      gload_lds16(Bmat + (size_t)(bn * 128 + row) * C_ + k0 + col, &Bs[e]);
    }
    asm volatile("s_waitcnt vmcnt(0)" ::: "memory");
    __syncthreads();

    bf16x8 af[4], bfr[4];
#pragma unroll
    for (int m = 0; m < 4; ++m)
      af[m] = *(const bf16x8*)&As[(wr * 64 + m * 16 + lrow) * 32 + lk];
#pragma unroll
    for (int n = 0; n < 4; ++n)
      bfr[n] = *(const bf16x8*)&Bs[(wc * 64 + n * 16 + lrow) * 32 + lk];
#pragma unroll
    for (int m = 0; m < 4; ++m)
#pragma unroll
      for (int n = 0; n < 4; ++n)
        acc[m][n] = __builtin_amdgcn_mfma_f32_16x16x32_bf16(af[m], bfr[n],
                                                            acc[m][n], 0, 0, 0);
    __syncthreads();
  }

#pragma unroll
  for (int m = 0; m < 4; ++m) {
#pragma unroll
    for (int n = 0; n < 4; ++n) {
      f32x4 v = acc[m][n];
      int rowm = bm * 128 + wr * 64 + m * 16 + (lane >> 4) * 4;
      int coln = bn * 128 + wc * 64 + n * 16 + (lane & 15);
      if (z == 2) {
        int b = coln >> 11, tl = coln & 2047;
#pragma unroll
        for (int r = 0; r < 4; ++r) {
          int rc = rowm + r;
          int h = rc >> 6, d = rc & 63;
          VTo[(((size_t)(b * H_ + h)) * D_ + d) * T_ + tl] =
              __float2bfloat16(v[r] + bv[rc]);
        }
      } else {
        float bb = (z == 0) ? bq[coln] : 0.f;
        // Q pre-scale: D^-0.5 * log2(e) so attention works in exp2 domain
        float sc = (z == 0) ? 0.18033688011112042f : 1.0f;
        int h = coln >> 6, d = coln & 63;
        __hip_bfloat16* Out = (z == 0) ? Qo : Ko;
#pragma unroll
        for (int r = 0; r < 4; ++r) {
          int row = rowm + r;
          int b = row >> 11, t = row & 2047;
          Out[(((size_t)(b * H_ + h)) * T_ + t) * D_ + d] =
              __float2bfloat16((v[r] + bb) * sc);
        }
      }
    }
  }
}

// ---------------- output projection GEMM (fp32 out) ----------------
__global__ __launch_bounds__(256) void gemm_out(
    const __hip_bfloat16* __restrict__ X,
    const __hip_bfloat16* __restrict__ W,
    const float* __restrict__ bias, float* __restrict__ Out) {
  const int bm = ((blockIdx.x & 3) << 3) | (blockIdx.x >> 2);
  const int bn = blockIdx.y;
  const int tid = threadIdx.x;
  const int w = tid >> 6, lane = tid & 63;
  const int wr = w >> 1, wc = w & 1;
  const int lrow = lane & 15, lk = (lane >> 4) * 8;

  __shared__ __hip_bfloat16 As[128 * 32];
  __shared__ __hip_bfloat16 Bs[128 * 32];

  f32x4 acc[4][4];
#pragma unroll
  for (int m = 0; m < 4; ++m)
#pragma unroll
    for (int n = 0; n < 4; ++n) acc[m][n] = (f32x4){0.f, 0.f, 0.f, 0.f};

  for (int k0 = 0; k0 < C_; k0 += 32) {
#pragma unroll
    for (int it = 0; it < 2; ++it) {
      int e = it * 2048 + w * 512 + lane * 8;
      int row = e >> 5, col = e & 31;
      gload_lds16(X + (size_t)(bm * 128 + row) * C_ + k0 + col, &As[e]);
      gload_lds16(W + (size_t)(bn * 128 + row) * C_ + k0 + col, &Bs[e]);
    }
    asm volatile("s_waitcnt vmcnt(0)" ::: "memory");
    __syncthreads();

    bf16x8 af[4], bfr[4];
#pragma unroll
    for (int m = 0; m < 4; ++m)
      af[m] = *(const bf16x8*)&As[(wr * 64 + m * 16 + lrow) * 32 + lk];
#pragma unroll
    for (int n = 0; n < 4; ++n)
      bfr[n] = *(const bf16x8*)&Bs[(wc * 64 + n * 16 + lrow) * 32 + lk];
#pragma unroll
    for (int m = 0; m < 4; ++m)
#pragma unroll
      for (int n = 0; n < 4; ++n)
        acc[m][n] = __builtin_amdgcn_mfma_f32_16x16x32_bf16(af[m], bfr[n],
                                                            acc[m][n], 0, 0, 0);
    __syncthreads();
  }

#pragma unroll
  for (int m = 0; m < 4; ++m) {
#pragma unroll
    for (int n = 0; n < 4; ++n) {
      f32x4 v = acc[m][n];
      int coln = bn * 128 + wc * 64 + n * 16 + (lane & 15);
      float bb = bias[coln];
#pragma unroll
      for (int r = 0; r < 4; ++r) {
        int row = bm * 128 + wr * 64 + m * 16 + (lane >> 4) * 4 + r;
        Out[(size_t)row * C_ + coln] = v[r] + bb;
      }
    }
  }
}

// ---------------- flash attention (causal), paired q-tiles, exp2 domain ----
// grid (32, 8): x = bh (bh-major so a bh's blocks share an XCD), y = pair j.
// Block processes q-tiles j and 15-j sequentially -> uniform 17 kv-iters/g.
#define MASKV_ -1e30f
#define MFLOOR_ -30000.0f
#define THR2_ 11.54f  // 8 * log2(e)

__global__ __launch_bounds__(512, 2) void attn_fwd(
    const __hip_bfloat16* __restrict__ Q, const __hip_bfloat16* __restrict__ K,
    const __hip_bfloat16* __restrict__ VT, __hip_bfloat16* __restrict__ Y) {
  const int bh = blockIdx.x;
  const int j = blockIdx.y;  // pair index 0..7
  const int tid = threadIdx.x;
  const int wid = tid >> 6, lane = tid & 63;
  const int g = wid >> 2, wq = wid & 3;
  const int hi = lane >> 5, q32 = lane & 31;
  const size_t base = (size_t)bh * T_ * D_;
  const int b = bh >> 4, hh = bh & 15;

  __shared__ __hip_bfloat16 Ks[2][2][64][64];   // [g][buf]
  __shared__ __hip_bfloat16 Vts[2][2][64][64];  // [g][buf]
  __shared__ float Sml[2][4][2][32];
  __shared__ float Om[4][32][68];

  const int gt = tid & 255;
  const int srow = gt >> 3, scnk = gt & 7;
  const int swz = (scnk ^ (srow & 7)) * 8;  // pre-swizzled source chunk

#define STAGE(buf, kt)                                                      \
  {                                                                         \
    _Pragma("unroll") for (int h2 = 0; h2 < 2; ++h2) {                      \
      int row = srow + 32 * h2;                                             \
      gload_lds16(K + base + (size_t)((kt)*64 + row) * D_ + swz,            \
                  &Ks[g][(buf)][row][scnk * 8]);                            \
      gload_lds16(VT + base + (size_t)row * T_ + (kt)*64 + swz,             \
                  &Vts[g][(buf)][row][scnk * 8]);                           \
    }                                                                       \
  }

  for (int ph = 0; ph < 2; ++ph) {
    const int qt = ph ? (15 - j) : j;
    const int qg = qt * 128 + wq * 32 + q32;

    bf16x8 qf[4];
#pragma unroll
    for (int dk = 0; dk < 4; ++dk)
      qf[dk] = *(const bf16x8*)&Q[base + (size_t)qg * D_ + dk * 16 + hi * 8];

    f32x16 o0 = {}, o1 = {};
    float m_run = MFLOOR_, l_run = 0.f;

    // phase prologue: stage tile s=0
    STAGE(0, g);
    asm volatile("s_waitcnt vmcnt(0)" ::: "memory");
    __syncthreads();

    int cur = 0;
    for (int s = 0; s <= qt; ++s) {
      const int kt = 2 * s + g;
      if (s < qt) STAGE(cur ^ 1, 2 * (s + 1) + g);  // prefetch next (hidden)

      // QK^T swapped: lane owns q=lane&31
      f32x16 st0 = {}, st1 = {};
      __builtin_amdgcn_s_setprio(1);
#pragma unroll
      for (int dk = 0; dk < 4; ++dk) {
        int off = (dk * 16 + hi * 8) ^ ((lane & 7) << 3);
        bf16x8 a0 = *(const bf16x8*)&Ks[g][cur][q32][off];
        bf16x8 a1 = *(const bf16x8*)&Ks[g][cur][q32 + 32][off];
        st0 = __builtin_amdgcn_mfma_f32_32x32x16_bf16(a0, qf[dk], st0, 0, 0, 0);
        st1 = __builtin_amdgcn_mfma_f32_32x32x16_bf16(a1, qf[dk], st1, 0, 0, 0);
      }
      __builtin_amdgcn_s_setprio(0);

      float sc[32];
#pragma unroll
      for (int r = 0; r < 16; ++r) {
        sc[r] = st0[r];
        sc[16 + r] = st1[r];
      }
      if (s == qt) {  // diagonal: causal mask
#pragma unroll
        for (int r = 0; r < 16; ++r) {
          int kvl = (r & 3) + 8 * (r >> 2) + 4 * hi;
          if (kt * 64 + kvl > qg) sc[r] = MASKV_;
          if (kt * 64 + 32 + kvl > qg) sc[16 + r] = MASKV_;
        }
      }
      float mt = sc[0];
#pragma unroll
      for (int r = 1; r < 32; ++r) mt = fmaxf(mt, sc[r]);
      mt = fmaxf(mt, __shfl_xor(mt, 32));
      if (__any(mt - m_run > THR2_)) {  // defer-max (T13)
        float m_new = fmaxf(m_run, mt);
        float alpha = __builtin_exp2f(m_run - m_new);
        m_run = m_new;
        l_run *= alpha;
#pragma unroll
        for (int r = 0; r < 16; ++r) {
          o0[r] *= alpha;
          o1[r] *= alpha;
        }
      }
      float ls = 0.f;
#pragma unroll
      for (int r = 0; r < 32; ++r) {
        float p = __builtin_exp2f(sc[r] - m_run);
        sc[r] = p;
        ls += p;
      }
      ls += __shfl_xor(ls, 32);
      l_run += ls;

      // pack P to bf16 B-fragments (cvt_pk + permlane32_swap) and PV
      __builtin_amdgcn_s_setprio(1);
#pragma unroll
      for (int ks = 0; ks < 4; ++ks) {
        union { unsigned w[4]; bf16x8 v; } pa;
        unsigned A, Bb;
        asm("v_cvt_pk_bf16_f32 %0, %1, %2"
            : "=v"(A) : "v"(sc[ks * 8 + 0]), "v"(sc[ks * 8 + 1]));
        asm("v_cvt_pk_bf16_f32 %0, %1, %2"
            : "=v"(Bb) : "v"(sc[ks * 8 + 4]), "v"(sc[ks * 8 + 5]));
        asm volatile("v_permlane32_swap_b32 %0, %1" : "+v"(A), "+v"(Bb));
        pa.w[0] = A;
        pa.w[2] = Bb;
        asm("v_cvt_pk_bf16_f32 %0, %1, %2"
            : "=v"(A) : "v"(sc[ks * 8 + 2]), "v"(sc[ks * 8 + 3]));
        asm("v_cvt_pk_bf16_f32 %0, %1, %2"
            : "=v"(Bb) : "v"(sc[ks * 8 + 6]), "v"(sc[ks * 8 + 7]));
        asm volatile("v_permlane32_swap_b32 %0, %1" : "+v"(A), "+v"(Bb));
        pa.w[1] = A;
        pa.w[3] = Bb;

        int voff = (ks * 16 + hi * 8) ^ ((lane & 7) << 3);
        bf16x8 v0 = *(const bf16x8*)&Vts[g][cur][q32][voff];
        bf16x8 v1 = *(const bf16x8*)&Vts[g][cur][q32 + 32][voff];
        o0 = __builtin_amdgcn_mfma_f32_32x32x16_bf16(v0, pa.v, o0, 0, 0, 0);
        o1 = __builtin_amdgcn_mfma_f32_32x32x16_bf16(v1, pa.v, o1, 0, 0, 0);
      }
      __builtin_amdgcn_s_setprio(0);

      asm volatile("s_waitcnt vmcnt(0)" ::: "memory");  // next tile landed
      __syncthreads();
      cur ^= 1;
    }

    // merge the two kv-split groups
    if (lane < 32) {
      Sml[g][wq][0][lane] = m_run;
      Sml[g][wq][1][lane] = l_run;
    }
    __syncthreads();
    float mo = Sml[1 - g][wq][0][q32];
    float lo_ = Sml[1 - g][wq][1][q32];
    float mstar = fmaxf(m_run, mo);
    float f = __builtin_exp2f(m_run - mstar);
    float fo = __builtin_exp2f(mo - mstar);
    float lstar = l_run * f + lo_ * fo;

    if (g == 1) {
#pragma unroll
      for (int dt = 0; dt < 2; ++dt) {
#pragma unroll
        for (int grp = 0; grp < 4; ++grp) {
          int dbase = grp * 8 + hi * 4 + dt * 32;
          float4 t4;
          t4.x = (dt ? o1[grp * 4 + 0] : o0[grp * 4 + 0]) * f;
          t4.y = (dt ? o1[grp * 4 + 1] : o0[grp * 4 + 1]) * f;
          t4.z = (dt ? o1[grp * 4 + 2] : o0[grp * 4 + 2]) * f;
          t4.w = (dt ? o1[grp * 4 + 3] : o0[grp * 4 + 3]) * f;
          *(float4*)&Om[wq][q32][dbase] = t4;
        }
      }
    }
    __syncthreads();
    if (g == 0) {
      float inv = 1.0f / lstar;
#pragma unroll
      for (int dt = 0; dt < 2; ++dt) {
#pragma unroll
        for (int grp = 0; grp < 4; ++grp) {
          int dbase = grp * 8 + hi * 4 + dt * 32;
          float4 m4 = *(float4*)&Om[wq][q32][dbase];
          union { __hip_bfloat16 h4[4]; ushort4 u; } pk;
          float e0 = (dt ? o1[grp * 4 + 0] : o0[grp * 4 + 0]) * f + m4.x;
          float e1 = (dt ? o1[grp * 4 + 1] : o0[grp * 4 + 1]) * f + m4.y;
          float e2 = (dt ? o1[grp * 4 + 2] : o0[grp * 4 + 2]) * f + m4.z;
          float e3 = (dt ? o1[grp * 4 + 3] : o0[grp * 4 + 3]) * f + m4.w;
          pk.h4[0] = __float2bfloat16(e0 * inv);
          pk.h4[1] = __float2bfloat16(e1 * inv);
          pk.h4[2] = __float2bfloat16(e2 * inv);
          pk.h4[3] = __float2bfloat16(e3 * inv);
          *(ushort4*)&Y[((size_t)b * T_ + qg) * C_ + hh * 64 + dbase] = pk.u;
        }
      }
    }
    __syncthreads();  // protect Sml/Om/LDS before next phase
  }
}

extern "C" void kernel_launch(void* const* d_in, const int* in_sizes, int n_in,
                              void* d_out, int out_size, void* d_ws,
                              size_t ws_size, hipStream_t stream) {
  const float* x = (const float*)d_in[0];
  const float* Wk = (const float*)d_in[1];
  const float* Wq = (const float*)d_in[2];
  const float* bq = (const float*)d_in[3];
  const float* Wv = (const float*)d_in[4];
  const float* bv = (const float*)d_in[5];
  const float* Wo = (const float*)d_in[6];
  const float* bo = (const float*)d_in[7];
  float* out = (float*)d_out;

  char* ws = (char*)d_ws;
  __hip_bfloat16* xb = (__hip_bfloat16*)(ws);
  __hip_bfloat16* wqb = (__hip_bfloat16*)(ws + (8ull << 20));
  __hip_bfloat16* wkb = (__hip_bfloat16*)(ws + (10ull << 20));
  __hip_bfloat16* wvb = (__hip_bfloat16*)(ws + (12ull << 20));
  __hip_bfloat16* wob = (__hip_bfloat16*)(ws + (14ull << 20));
  __hip_bfloat16* Qb = (__hip_bfloat16*)(ws + (16ull << 20));
  __hip_bfloat16* Kb = (__hip_bfloat16*)(ws + (24ull << 20));
  __hip_bfloat16* VTb = (__hip_bfloat16*)(ws + (32ull << 20));
  __hip_bfloat16* Yb = (__hip_bfloat16*)(ws + (40ull << 20));

  cvt_all<<<8192, 256, 0, stream>>>(x, Wq, Wk, Wv, Wo, xb, wqb, wkb, wvb, wob);
  gemm_qkv<<<dim3(32, 8, 3), 256, 0, stream>>>(xb, wqb, wkb, wvb, bq, bv, Qb,
                                               Kb, VTb);
  attn_fwd<<<dim3(32, 8), 512, 0, stream>>>(Qb, Kb, VTb, Yb);
  gemm_out<<<dim3(32, 8), 256, 0, stream>>>(Yb, wob, bo, out);
}